// Round 22
// baseline (99.642 us; speedup 1.0000x reference)
//
#include <hip/hip_runtime.h>
#include <hip/hip_bf16.h>

#define D_ 128
#define E_ 100
#define K_ 4
#define C_ 400
#define NCHUNK 128     // atom chunks in k_sums3 (x2 dim-halves = 256 blocks)
#define SCALE 65536.0f
#define INV_SCALE (1.0f / 65536.0f)

// ws layout (f32/u32 slots):
#define OFF_COUNTS 51200
#define OFF_LOSS   51600
#define OFF_CB16   51712                     // u32[400*64]: fp16 codebook
#define OFF_PSUM   (OFF_CB16 + 25600)
#define PSUM_SZ    (256 * C_ * 64)
#define OFF_PCNT   (OFF_PSUM + PSUM_SZ)
#define WS_NEED_PART ((size_t)(OFF_PCNT + NCHUNK * C_) * 4)
#define WS_NEED_CB16 ((size_t)(OFF_CB16 + 25600) * 4)

typedef float f32x4 __attribute__((ext_vector_type(4)));

__device__ __forceinline__ void nt_store4(float4 v, float4* p) {
  __builtin_nontemporal_store(__builtin_bit_cast(f32x4, v), (f32x4*)p);
}

template <int CTRL>
__device__ __forceinline__ float dpp_add(float x) {
  int y = __builtin_amdgcn_update_dpp(0, __builtin_bit_cast(int, x),
                                      CTRL, 0xF, 0xF, true);
  return x + __builtin_bit_cast(float, y);
}

__device__ __forceinline__ float2 cvt2(unsigned u) {
  _Float16 lo = __builtin_bit_cast(_Float16, (unsigned short)(u & 0xFFFFu));
  _Float16 hi = __builtin_bit_cast(_Float16, (unsigned short)(u >> 16));
  return make_float2((float)lo, (float)hi);
}

__device__ __forceinline__ unsigned pack2(float a, float b) {
  unsigned short qa = __builtin_bit_cast(unsigned short, (_Float16)a);
  unsigned short qb = __builtin_bit_cast(unsigned short, (_Float16)b);
  return (unsigned)qa | ((unsigned)qb << 16);
}

// squared distance of lane's 8 dims vs one fp16-packed row-slot
__device__ __forceinline__ float dist8u(float4 hA, float4 hB, uint4 r) {
  float2 a0 = cvt2(r.x), a1 = cvt2(r.y), a2 = cvt2(r.z), a3 = cvt2(r.w);
  float d0 = hA.x - a0.x, d1 = hA.y - a0.y;
  float d2 = hA.z - a1.x, d3 = hA.w - a1.y;
  float d4 = hB.x - a2.x, d5 = hB.y - a2.y;
  float d6 = hB.z - a3.x, d7 = hB.w - a3.y;
  return ((d0*d0 + d1*d1) + (d2*d2 + d3*d3)) +
         ((d4*d4 + d5*d5) + (d6*d6 + d7*d7));
}

// Prep: cb (f32) -> cb16 (fp16, dense-halves permuted).
// Slot (c,t): dims {4t..4t+3} and {64+4t..64+4t+3} of row c.
__global__ __launch_bounds__(256) void k_cvt(
    const float* __restrict__ cb, unsigned* __restrict__ cb16) {
  int idx = blockIdx.x * 256 + threadIdx.x;     // 6400 slots
  if (idx >= C_ * 16) return;
  int c = idx >> 4, t = idx & 15;
  const float4* cb4 = (const float4*)cb;
  float4 u = cb4[c * 32 + t];
  float4 v = cb4[c * 32 + 16 + t];
  uint4 r;
  r.x = pack2(u.x, u.y);
  r.y = pack2(u.z, u.w);
  r.z = pack2(v.x, v.y);
  r.w = pack2(v.z, v.w);
  ((uint4*)cb16)[idx] = r;
}

// Kernel 1 (primary): streaming argmin with fp16 codebook.
// 16 lanes/atom, dense-halves; ONE cb load per codebook row (256B dense);
// ~50 VGPR -> 8 waves/SIMD; 1-deep h/ei prefetch; nt hq stores.
__global__ __launch_bounds__(256) void k_assign16(
    const float* __restrict__ h, const int* __restrict__ ei,
    const unsigned* __restrict__ cb16, float* __restrict__ hq,
    float* __restrict__ at, float* __restrict__ loss_acc, int N) {
  const int t = threadIdx.x & 15;
  const int gid = (blockIdx.x * 256 + threadIdx.x) >> 4;
  const int ng = (gridDim.x * 256) >> 4;
  const float4* h4 = (const float4*)h;
  const uint4* cbu = (const uint4*)cb16;
  float4* hq4 = (float4*)hq;
  float loss = 0.f;

  int a = gid;
  bool ok = a < N;
  const int as = ok ? a : 0;
  int e = ei[as];
  float4 hA = h4[(size_t)as * 32 + t];
  float4 hB = h4[(size_t)as * 32 + 16 + t];

  while (ok) {
    const int an = a + ng;
    const bool okn = an < N;
    const int ans = okn ? an : a;
    const int en = ei[ans];
    const float4 hAn = h4[(size_t)ans * 32 + t];
    const float4 hBn = h4[(size_t)ans * 32 + 16 + t];

    // 4 row loads, each one dense 256B segment per 16-lane group
    const int cbase = e * (K_ * 16) + t;
    const uint4 r0 = cbu[cbase];
    const uint4 r1 = cbu[cbase + 16];
    const uint4 r2 = cbu[cbase + 32];
    const uint4 r3 = cbu[cbase + 48];

    float p0 = dist8u(hA, hB, r0);
    float p1 = dist8u(hA, hB, r1);
    float p2 = dist8u(hA, hB, r2);
    float p3 = dist8u(hA, hB, r3);

    // 16-lane group reduce: pure-VALU DPP butterfly
    p0 = dpp_add<0xB1>(p0); p1 = dpp_add<0xB1>(p1);
    p2 = dpp_add<0xB1>(p2); p3 = dpp_add<0xB1>(p3);
    p0 = dpp_add<0x4E>(p0); p1 = dpp_add<0x4E>(p1);
    p2 = dpp_add<0x4E>(p2); p3 = dpp_add<0x4E>(p3);
    p0 = dpp_add<0x141>(p0); p1 = dpp_add<0x141>(p1);
    p2 = dpp_add<0x141>(p2); p3 = dpp_add<0x141>(p3);
    p0 = dpp_add<0x140>(p0); p1 = dpp_add<0x140>(p1);
    p2 = dpp_add<0x140>(p2); p3 = dpp_add<0x140>(p3);

    int best = 0; float bp = p0;
    if (p1 < bp) { bp = p1; best = 1; }
    if (p2 < bp) { bp = p2; best = 2; }
    if (p3 < bp) { bp = p3; best = 3; }

    uint4 qr = r0;
    if (best == 1) qr = r1;
    if (best == 2) qr = r2;
    if (best == 3) qr = r3;
    float2 q0 = cvt2(qr.x), q1 = cvt2(qr.y), q2 = cvt2(qr.z), q3 = cvt2(qr.w);
    nt_store4(make_float4(q0.x, q0.y, q1.x, q1.y), &hq4[(size_t)a * 32 + t]);
    nt_store4(make_float4(q2.x, q2.y, q3.x, q3.y), &hq4[(size_t)a * 32 + 16 + t]);
    if (t == 0) {
      at[a] = (float)(e * K_ + best);
      loss += bp;
    }

    a = an; ok = okn; e = en; hA = hAn; hB = hBn;
  }

  loss += __shfl_xor(loss, 16, 64);
  loss += __shfl_xor(loss, 32, 64);
  __shared__ float wl[4];
  const int w = threadIdx.x >> 6;
  if ((threadIdx.x & 63) == 0) wl[w] = loss;
  __syncthreads();
  if (threadIdx.x == 0)
    atomicAdd(loss_acc, wl[0] + wl[1] + wl[2] + wl[3]);
}

// Fallback (ws too small for cb16): r21 f32 single-chain.
__global__ __launch_bounds__(256) void k_assignf(
    const float* __restrict__ h, const int* __restrict__ ei,
    const float* __restrict__ cb, float* __restrict__ hq,
    float* __restrict__ at, float* __restrict__ loss_acc, int N) {
  const int t = threadIdx.x & 15;
  const int gid = (blockIdx.x * 256 + threadIdx.x) >> 4;
  const int ng = (gridDim.x * 256) >> 4;
  const float4* h4 = (const float4*)h;
  const float4* cb4 = (const float4*)cb;
  float4* hq4 = (float4*)hq;
  float loss = 0.f;
  int a = gid;
  bool ok = a < N;
  const int as = ok ? a : 0;
  int e = ei[as];
  float4 hA = h4[(size_t)as * 32 + t];
  float4 hB = h4[(size_t)as * 32 + 16 + t];
  while (ok) {
    const int an = a + ng;
    const bool okn = an < N;
    const int ans = okn ? an : a;
    const int en = ei[ans];
    const float4 hAn = h4[(size_t)ans * 32 + t];
    const float4 hBn = h4[(size_t)ans * 32 + 16 + t];
    const size_t cb0 = (size_t)e * 128 + t;
    float4 cA0 = cb4[cb0],      cB0 = cb4[cb0 + 16];
    float4 cA1 = cb4[cb0 + 32], cB1 = cb4[cb0 + 48];
    float4 cA2 = cb4[cb0 + 64], cB2 = cb4[cb0 + 80];
    float4 cA3 = cb4[cb0 + 96], cB3 = cb4[cb0 + 112];
    float d0, d1, d2, d3, d4, d5, d6, d7;
#define DIST(cA, cB, P) \
    d0 = hA.x - cA.x; d1 = hA.y - cA.y; d2 = hA.z - cA.z; d3 = hA.w - cA.w; \
    d4 = hB.x - cB.x; d5 = hB.y - cB.y; d6 = hB.z - cB.z; d7 = hB.w - cB.w; \
    float P = ((d0*d0 + d1*d1) + (d2*d2 + d3*d3)) + ((d4*d4 + d5*d5) + (d6*d6 + d7*d7));
    DIST(cA0, cB0, p0) DIST(cA1, cB1, p1) DIST(cA2, cB2, p2) DIST(cA3, cB3, p3)
#undef DIST
    p0 = dpp_add<0xB1>(p0); p1 = dpp_add<0xB1>(p1);
    p2 = dpp_add<0xB1>(p2); p3 = dpp_add<0xB1>(p3);
    p0 = dpp_add<0x4E>(p0); p1 = dpp_add<0x4E>(p1);
    p2 = dpp_add<0x4E>(p2); p3 = dpp_add<0x4E>(p3);
    p0 = dpp_add<0x141>(p0); p1 = dpp_add<0x141>(p1);
    p2 = dpp_add<0x141>(p2); p3 = dpp_add<0x141>(p3);
    p0 = dpp_add<0x140>(p0); p1 = dpp_add<0x140>(p1);
    p2 = dpp_add<0x140>(p2); p3 = dpp_add<0x140>(p3);
    int best = 0; float bp = p0;
    if (p1 < bp) { bp = p1; best = 1; }
    if (p2 < bp) { bp = p2; best = 2; }
    if (p3 < bp) { bp = p3; best = 3; }
    float4 qA = cA0, qB = cB0;
    if (best == 1) { qA = cA1; qB = cB1; }
    if (best == 2) { qA = cA2; qB = cB2; }
    if (best == 3) { qA = cA3; qB = cB3; }
    nt_store4(qA, &hq4[(size_t)a * 32 + t]);
    nt_store4(qB, &hq4[(size_t)a * 32 + 16 + t]);
    if (t == 0) { at[a] = (float)(e * K_ + best); loss += bp; }
    a = an; ok = okn; e = en; hA = hAn; hB = hBn;
  }
  loss += __shfl_xor(loss, 16, 64);
  loss += __shfl_xor(loss, 32, 64);
  __shared__ float wl[4];
  const int w = threadIdx.x >> 6;
  if ((threadIdx.x & 63) == 0) wl[w] = loss;
  __syncthreads();
  if (threadIdx.x == 0)
    atomicAdd(loss_acc, wl[0] + wl[1] + wl[2] + wl[3]);
}

// Kernel 2: streaming segment-sum + counts with NATIVE s32 LDS atomics.
__global__ __launch_bounds__(1024) void k_sums3(
    const float* __restrict__ h, const float* __restrict__ at,
    int* __restrict__ psumI, int* __restrict__ pcntI,
    float* __restrict__ sums, float* __restrict__ countsF,
    int dopart, int N) {
  const int half = blockIdx.x & 1;
  const int chunk = blockIdx.x >> 1;
  __shared__ int acc[C_ * 64];
  __shared__ int cnt[C_];
  for (int i = threadIdx.x; i < C_ * 64; i += 1024) acc[i] = 0;
  if (half == 0)
    for (int i = threadIdx.x; i < C_; i += 1024) cnt[i] = 0;
  __syncthreads();

  const int per = (N + NCHUNK - 1) / NCHUNK;
  const int a0 = chunk * per;
  const int aEnd = min(a0 + per, N);
  const int w = threadIdx.x >> 6;
  const int lane = threadIdx.x & 63;
  const int g = lane >> 4, t = lane & 15;
  const float4* h4 = (const float4*)h;

  int a = a0 + w * 4 + g;
  bool ok0 = a < aEnd, ok1 = (a + 64) < aEnd;
  float4 v0 = {}, v1 = {}; int c0 = 0, c1 = 0;
  if (ok0) { v0 = h4[(size_t)a * 32 + half * 16 + t]; c0 = (int)at[a]; }
  if (ok1) { v1 = h4[(size_t)(a + 64) * 32 + half * 16 + t]; c1 = (int)at[a + 64]; }

  while (ok0) {
    const int an = a + 128;
    const bool okn = an < aEnd;
    float4 vn = {}; int cn = 0;
    if (okn) { vn = h4[(size_t)an * 32 + half * 16 + t]; cn = (int)at[an]; }

    int* ap = &acc[c0 * 64 + t * 4];
    int iv0 = __float2int_rn(v0.x * SCALE);
    int iv1 = __float2int_rn(v0.y * SCALE);
    int iv2 = __float2int_rn(v0.z * SCALE);
    int iv3 = __float2int_rn(v0.w * SCALE);
    if (g == 0) { atomicAdd(&ap[0],iv0); atomicAdd(&ap[1],iv1); atomicAdd(&ap[2],iv2); atomicAdd(&ap[3],iv3); }
    else if (g == 1) { atomicAdd(&ap[1],iv1); atomicAdd(&ap[2],iv2); atomicAdd(&ap[3],iv3); atomicAdd(&ap[0],iv0); }
    else if (g == 2) { atomicAdd(&ap[2],iv2); atomicAdd(&ap[3],iv3); atomicAdd(&ap[0],iv0); atomicAdd(&ap[1],iv1); }
    else { atomicAdd(&ap[3],iv3); atomicAdd(&ap[0],iv0); atomicAdd(&ap[1],iv1); atomicAdd(&ap[2],iv2); }
    if (half == 0 && t == 0) atomicAdd(&cnt[c0], 1);

    a += 64;
    ok0 = ok1; v0 = v1; c0 = c1;
    ok1 = okn; v1 = vn; c1 = cn;
  }
  __syncthreads();

  if (dopart) {
    int* pb = psumI + (size_t)blockIdx.x * (C_ * 64);
    for (int i = threadIdx.x; i < C_ * 64; i += 1024) pb[i] = acc[i];
    if (half == 0) {
      int* pc = pcntI + (size_t)chunk * C_;
      for (int i = threadIdx.x; i < C_; i += 1024) pc[i] = cnt[i];
    }
  } else {
    for (int i = threadIdx.x; i < C_ * 64; i += 1024) {
      int vv = acc[i];
      if (vv != 0)
        atomicAdd(&sums[(size_t)(i >> 6) * D_ + half * 64 + (i & 63)],
                  (float)vv * INV_SCALE);
    }
    if (half == 0)
      for (int i = threadIdx.x; i < C_; i += 1024)
        if (cnt[i] != 0) atomicAdd(&countsF[i], (float)cnt[i]);
  }
}

// Kernel 3 (partials path): reduce s32 partials -> f32 sums, countsF.
__global__ __launch_bounds__(256) void k_reduce(
    const int* __restrict__ psumI, const int* __restrict__ pcntI,
    float* __restrict__ sums, float* __restrict__ countsF) {
  int idx = blockIdx.x * 256 + threadIdx.x;
  if (idx < C_ * D_) {
    int code = idx >> 7;
    int dim = idx & 127;
    int half = dim >> 6;
    int dl = dim & 63;
    const int* p = psumI + (size_t)half * (C_ * 64) + code * 64 + dl;
    float s = 0.f;
    for (int b = 0; b < NCHUNK; ++b)
      s += (float)p[(size_t)b * 2 * (C_ * 64)];
    sums[idx] = s * INV_SCALE;
  }
  if (idx < C_) {
    int s = 0;
    for (int b = 0; b < NCHUNK; ++b)
      s += pcntI[(size_t)b * C_ + idx];
    countsF[idx] = (float)s;
  }
}

// Kernel 4: EMA finalize + loss scalar.
__global__ __launch_bounds__(256) void k_final(
    const float* __restrict__ cb, const float* __restrict__ ecnt,
    const float* __restrict__ esum, const float* __restrict__ ws,
    float* __restrict__ out, int N) {
  const float* sums = ws;
  const float* countsF = ws + OFF_COUNTS;
  int idx = blockIdx.x * 256 + threadIdx.x;
  const size_t base = (size_t)N * D_ + N + 1;
  if (idx < C_ * D_) {
    int c = idx >> 7;
    int e4 = (c >> 2) << 2;
    bool present = (countsF[e4] + countsF[e4 + 1] + countsF[e4 + 2] + countsF[e4 + 3]) > 0.f;
    float es = esum[idx];
    float s  = sums[idx];
    float ns = present ? 0.99f * es + 0.01f * s : es;
    float ec = ecnt[c];
    float nc = present ? 0.99f * ec + 0.01f * countsF[c] : ec;
    float ncbv = present ? ns / fmaxf(nc, 1e-5f) : cb[idx];
    out[base + idx] = ncbv;
    if ((idx & 127) == 0) out[base + C_ * D_ + c] = nc;
    out[base + C_ * D_ + C_ + idx] = ns;
  }
  if (idx == 0) {
    float loss = ws[OFF_LOSS];
    out[(size_t)N * D_ + N] = 0.25f * loss / ((float)N * (float)D_);
  }
}

extern "C" void kernel_launch(void* const* d_in, const int* in_sizes, int n_in,
                              void* d_out, int out_size, void* d_ws, size_t ws_size,
                              hipStream_t stream) {
  // Identify inputs by size (robust to input-order changes).
  const float* h = nullptr; const int* ei = nullptr;
  const float* cb = nullptr; const float* ecnt = nullptr; const float* esum = nullptr;
  long hsz = -1; int hidx = -1;
  for (int i = 0; i < n_in; ++i)
    if ((long)in_sizes[i] > hsz) { hsz = in_sizes[i]; hidx = i; }
  h = (const float*)d_in[hidx];
  const int N = (int)(hsz / D_);
  for (int i = 0; i < n_in; ++i) {
    if (i == hidx) continue;
    const int s = in_sizes[i];
    if (s == N) ei = (const int*)d_in[i];
    else if (s == C_) ecnt = (const float*)d_in[i];
    else if (s == C_ * D_) { if (!cb) cb = (const float*)d_in[i]; else esum = (const float*)d_in[i]; }
  }

  float* out = (float*)d_out;
  float* hq  = out;
  float* at  = out + (size_t)N * D_;

  float* ws = (float*)d_ws;
  float*    sums    = ws;
  float*    countsF = ws + OFF_COUNTS;
  float*    lossp   = ws + OFF_LOSS;
  unsigned* cb16    = (unsigned*)(ws + OFF_CB16);
  int*      psumI   = (int*)(ws + OFF_PSUM);
  int*      pcntI   = (int*)(ws + OFF_PCNT);

  const int dopart   = (ws_size >= WS_NEED_PART) ? 1 : 0;
  const int havecb16 = (ws_size >= WS_NEED_CB16) ? 1 : 0;

  // zero sums/countsF/loss; cb16/psum fully overwritten
  hipMemsetAsync(d_ws, 0, (size_t)(OFF_LOSS + 1) * 4, stream);

  if (havecb16) {
    k_cvt<<<(C_ * 16 + 255) / 256, 256, 0, stream>>>(cb, cb16);
    k_assign16<<<2048, 256, 0, stream>>>(h, ei, cb16, hq, at, lossp, N);
  } else {
    k_assignf<<<2048, 256, 0, stream>>>(h, ei, cb, hq, at, lossp, N);
  }
  k_sums3<<<NCHUNK * 2, 1024, 0, stream>>>(h, at, psumI, pcntI,
                                           sums, countsF, dopart, N);
  if (dopart)
    k_reduce<<<(C_ * D_ + 255) / 256, 256, 0, stream>>>(psumI, pcntI, sums, countsF);
  k_final<<<(C_ * D_ + 255) / 256, 256, 0, stream>>>(cb, ecnt, esum, ws, out, N);
}

// Round 23
// 96.722 us; speedup vs baseline: 1.0302x; 1.0302x over previous
//
#include <hip/hip_runtime.h>
#include <hip/hip_bf16.h>

#define D_ 128
#define E_ 100
#define K_ 4
#define C_ 400
#define NCHUNK 128     // atom chunks in k_sums3 (x2 dim-halves = 256 blocks)
#define SCALE 65536.0f
#define INV_SCALE (1.0f / 65536.0f)

// ws layout (f32/i32 slots):
#define OFF_COUNTS 51200
#define OFF_LOSS   51600
#define OFF_PSUM   51712
#define PSUM_SZ    (256 * C_ * 64)
#define OFF_PCNT   (OFF_PSUM + PSUM_SZ)
#define WS_NEED_PART ((size_t)(OFF_PCNT + NCHUNK * C_) * 4)

typedef float f32x4 __attribute__((ext_vector_type(4)));

__device__ __forceinline__ void nt_store4(float4 v, float4* p) {
  __builtin_nontemporal_store(__builtin_bit_cast(f32x4, v), (f32x4*)p);
}

template <int CTRL>
__device__ __forceinline__ float dpp_add(float x) {
  int y = __builtin_amdgcn_update_dpp(0, __builtin_bit_cast(int, x),
                                      CTRL, 0xF, 0xF, true);
  return x + __builtin_bit_cast(float, y);
}

__device__ __forceinline__ float2 cvt2(unsigned u) {
  _Float16 lo = __builtin_bit_cast(_Float16, (unsigned short)(u & 0xFFFFu));
  _Float16 hi = __builtin_bit_cast(_Float16, (unsigned short)(u >> 16));
  return make_float2((float)lo, (float)hi);
}

__device__ __forceinline__ unsigned pack2(float a, float b) {
  unsigned short qa = __builtin_bit_cast(unsigned short, (_Float16)a);
  unsigned short qb = __builtin_bit_cast(unsigned short, (_Float16)b);
  return (unsigned)qa | ((unsigned)qb << 16);
}

// squared distance of lane's 8 dims vs one fp16-packed row-slot
__device__ __forceinline__ float dist8u(float4 hA, float4 hB, uint4 r) {
  float2 a0 = cvt2(r.x), a1 = cvt2(r.y), a2 = cvt2(r.z), a3 = cvt2(r.w);
  float d0 = hA.x - a0.x, d1 = hA.y - a0.y;
  float d2 = hA.z - a1.x, d3 = hA.w - a1.y;
  float d4 = hB.x - a2.x, d5 = hB.y - a2.y;
  float d6 = hB.z - a3.x, d7 = hB.w - a3.y;
  return ((d0*d0 + d1*d1) + (d2*d2 + d3*d3)) +
         ((d4*d4 + d5*d5) + (d6*d6 + d7*d7));
}

// Kernel 1: streaming argmin with the ENTIRE fp16 codebook in LDS (102.4 KB).
// 1024-thr blocks (1/CU), in-kernel stage+convert, 16 lanes/atom dense-halves,
// rows via ds_read_b128 (256B dense per group), DPP reduce, nt hq stores,
// 1-deep h/ei prefetch. Zero per-atom global cb traffic.
__global__ __launch_bounds__(1024) void k_assign_lds(
    const float* __restrict__ h, const int* __restrict__ ei,
    const float* __restrict__ cb, float* __restrict__ hq,
    float* __restrict__ at, float* __restrict__ loss_acc, int N) {
  __shared__ __align__(16) uint4 cbl[C_ * 16];   // slot (c,t): dims {4t..4t+3, 64+4t..}
  __shared__ float wl[16];
  const int tid = threadIdx.x;
  {
    const float4* cb4 = (const float4*)cb;
    for (int idx = tid; idx < C_ * 16; idx += 1024) {
      int c = idx >> 4, tt = idx & 15;
      float4 u = cb4[c * 32 + tt];
      float4 v = cb4[c * 32 + 16 + tt];
      uint4 r;
      r.x = pack2(u.x, u.y); r.y = pack2(u.z, u.w);
      r.z = pack2(v.x, v.y); r.w = pack2(v.z, v.w);
      cbl[idx] = r;
    }
  }
  __syncthreads();

  const int t = tid & 15;
  const int gid = blockIdx.x * 64 + (tid >> 4);
  const int ng = gridDim.x * 64;
  const float4* h4 = (const float4*)h;
  float4* hq4 = (float4*)hq;
  float loss = 0.f;

  int a = gid;
  bool ok = a < N;
  const int as = ok ? a : 0;
  int e = ei[as];
  float4 hA = h4[(size_t)as * 32 + t];
  float4 hB = h4[(size_t)as * 32 + 16 + t];

  while (ok) {
    const int an = a + ng;
    const bool okn = an < N;
    const int ans = okn ? an : a;
    const int en = ei[ans];
    const float4 hAn = h4[(size_t)ans * 32 + t];
    const float4 hBn = h4[(size_t)ans * 32 + 16 + t];

    const int cbase = e * (K_ * 16) + t;
    const uint4 r0 = cbl[cbase];
    const uint4 r1 = cbl[cbase + 16];
    const uint4 r2 = cbl[cbase + 32];
    const uint4 r3 = cbl[cbase + 48];

    float p0 = dist8u(hA, hB, r0);
    float p1 = dist8u(hA, hB, r1);
    float p2 = dist8u(hA, hB, r2);
    float p3 = dist8u(hA, hB, r3);

    // 16-lane group reduce: pure-VALU DPP butterfly
    p0 = dpp_add<0xB1>(p0); p1 = dpp_add<0xB1>(p1);
    p2 = dpp_add<0xB1>(p2); p3 = dpp_add<0xB1>(p3);
    p0 = dpp_add<0x4E>(p0); p1 = dpp_add<0x4E>(p1);
    p2 = dpp_add<0x4E>(p2); p3 = dpp_add<0x4E>(p3);
    p0 = dpp_add<0x141>(p0); p1 = dpp_add<0x141>(p1);
    p2 = dpp_add<0x141>(p2); p3 = dpp_add<0x141>(p3);
    p0 = dpp_add<0x140>(p0); p1 = dpp_add<0x140>(p1);
    p2 = dpp_add<0x140>(p2); p3 = dpp_add<0x140>(p3);

    int best = 0; float bp = p0;
    if (p1 < bp) { bp = p1; best = 1; }
    if (p2 < bp) { bp = p2; best = 2; }
    if (p3 < bp) { bp = p3; best = 3; }

    uint4 qr = r0;
    if (best == 1) qr = r1;
    if (best == 2) qr = r2;
    if (best == 3) qr = r3;
    float2 q0 = cvt2(qr.x), q1 = cvt2(qr.y), q2 = cvt2(qr.z), q3 = cvt2(qr.w);
    nt_store4(make_float4(q0.x, q0.y, q1.x, q1.y), &hq4[(size_t)a * 32 + t]);
    nt_store4(make_float4(q2.x, q2.y, q3.x, q3.y), &hq4[(size_t)a * 32 + 16 + t]);
    if (t == 0) {
      at[a] = (float)(e * K_ + best);
      loss += bp;
    }

    a = an; ok = okn; e = en; hA = hAn; hB = hBn;
  }

  loss += __shfl_xor(loss, 16, 64);
  loss += __shfl_xor(loss, 32, 64);
  if ((tid & 63) == 0) wl[tid >> 6] = loss;
  __syncthreads();
  if (tid == 0) {
    float s = 0.f;
#pragma unroll
    for (int i = 0; i < 16; ++i) s += wl[i];
    atomicAdd(loss_acc, s);
  }
}

// Kernel 2: streaming segment-sum + counts with NATIVE s32 LDS atomics.
__global__ __launch_bounds__(1024) void k_sums3(
    const float* __restrict__ h, const float* __restrict__ at,
    int* __restrict__ psumI, int* __restrict__ pcntI,
    float* __restrict__ sums, float* __restrict__ countsF,
    int dopart, int N) {
  const int half = blockIdx.x & 1;
  const int chunk = blockIdx.x >> 1;
  __shared__ int acc[C_ * 64];
  __shared__ int cnt[C_];
  for (int i = threadIdx.x; i < C_ * 64; i += 1024) acc[i] = 0;
  if (half == 0)
    for (int i = threadIdx.x; i < C_; i += 1024) cnt[i] = 0;
  __syncthreads();

  const int per = (N + NCHUNK - 1) / NCHUNK;
  const int a0 = chunk * per;
  const int aEnd = min(a0 + per, N);
  const int w = threadIdx.x >> 6;
  const int lane = threadIdx.x & 63;
  const int g = lane >> 4, t = lane & 15;
  const float4* h4 = (const float4*)h;

  int a = a0 + w * 4 + g;
  bool ok0 = a < aEnd, ok1 = (a + 64) < aEnd;
  float4 v0 = {}, v1 = {}; int c0 = 0, c1 = 0;
  if (ok0) { v0 = h4[(size_t)a * 32 + half * 16 + t]; c0 = (int)at[a]; }
  if (ok1) { v1 = h4[(size_t)(a + 64) * 32 + half * 16 + t]; c1 = (int)at[a + 64]; }

  while (ok0) {
    const int an = a + 128;
    const bool okn = an < aEnd;
    float4 vn = {}; int cn = 0;
    if (okn) { vn = h4[(size_t)an * 32 + half * 16 + t]; cn = (int)at[an]; }

    int* ap = &acc[c0 * 64 + t * 4];
    int iv0 = __float2int_rn(v0.x * SCALE);
    int iv1 = __float2int_rn(v0.y * SCALE);
    int iv2 = __float2int_rn(v0.z * SCALE);
    int iv3 = __float2int_rn(v0.w * SCALE);
    if (g == 0) { atomicAdd(&ap[0],iv0); atomicAdd(&ap[1],iv1); atomicAdd(&ap[2],iv2); atomicAdd(&ap[3],iv3); }
    else if (g == 1) { atomicAdd(&ap[1],iv1); atomicAdd(&ap[2],iv2); atomicAdd(&ap[3],iv3); atomicAdd(&ap[0],iv0); }
    else if (g == 2) { atomicAdd(&ap[2],iv2); atomicAdd(&ap[3],iv3); atomicAdd(&ap[0],iv0); atomicAdd(&ap[1],iv1); }
    else { atomicAdd(&ap[3],iv3); atomicAdd(&ap[0],iv0); atomicAdd(&ap[1],iv1); atomicAdd(&ap[2],iv2); }
    if (half == 0 && t == 0) atomicAdd(&cnt[c0], 1);

    a += 64;
    ok0 = ok1; v0 = v1; c0 = c1;
    ok1 = okn; v1 = vn; c1 = cn;
  }
  __syncthreads();

  if (dopart) {
    int* pb = psumI + (size_t)blockIdx.x * (C_ * 64);
    for (int i = threadIdx.x; i < C_ * 64; i += 1024) pb[i] = acc[i];
    if (half == 0) {
      int* pc = pcntI + (size_t)chunk * C_;
      for (int i = threadIdx.x; i < C_; i += 1024) pc[i] = cnt[i];
    }
  } else {
    for (int i = threadIdx.x; i < C_ * 64; i += 1024) {
      int vv = acc[i];
      if (vv != 0)
        atomicAdd(&sums[(size_t)(i >> 6) * D_ + half * 64 + (i & 63)],
                  (float)vv * INV_SCALE);
    }
    if (half == 0)
      for (int i = threadIdx.x; i < C_; i += 1024)
        if (cnt[i] != 0) atomicAdd(&countsF[i], (float)cnt[i]);
  }
}

// Kernel 3 (partials path): reduce s32 partials -> f32 sums, countsF.
__global__ __launch_bounds__(256) void k_reduce(
    const int* __restrict__ psumI, const int* __restrict__ pcntI,
    float* __restrict__ sums, float* __restrict__ countsF) {
  int idx = blockIdx.x * 256 + threadIdx.x;
  if (idx < C_ * D_) {
    int code = idx >> 7;
    int dim = idx & 127;
    int half = dim >> 6;
    int dl = dim & 63;
    const int* p = psumI + (size_t)half * (C_ * 64) + code * 64 + dl;
    float s = 0.f;
    for (int b = 0; b < NCHUNK; ++b)
      s += (float)p[(size_t)b * 2 * (C_ * 64)];
    sums[idx] = s * INV_SCALE;
  }
  if (idx < C_) {
    int s = 0;
    for (int b = 0; b < NCHUNK; ++b)
      s += pcntI[(size_t)b * C_ + idx];
    countsF[idx] = (float)s;
  }
}

// Kernel 4: EMA finalize + loss scalar.
__global__ __launch_bounds__(256) void k_final(
    const float* __restrict__ cb, const float* __restrict__ ecnt,
    const float* __restrict__ esum, const float* __restrict__ ws,
    float* __restrict__ out, int N) {
  const float* sums = ws;
  const float* countsF = ws + OFF_COUNTS;
  int idx = blockIdx.x * 256 + threadIdx.x;
  const size_t base = (size_t)N * D_ + N + 1;
  if (idx < C_ * D_) {
    int c = idx >> 7;
    int e4 = (c >> 2) << 2;
    bool present = (countsF[e4] + countsF[e4 + 1] + countsF[e4 + 2] + countsF[e4 + 3]) > 0.f;
    float es = esum[idx];
    float s  = sums[idx];
    float ns = present ? 0.99f * es + 0.01f * s : es;
    float ec = ecnt[c];
    float nc = present ? 0.99f * ec + 0.01f * countsF[c] : ec;
    float ncbv = present ? ns / fmaxf(nc, 1e-5f) : cb[idx];
    out[base + idx] = ncbv;
    if ((idx & 127) == 0) out[base + C_ * D_ + c] = nc;
    out[base + C_ * D_ + C_ + idx] = ns;
  }
  if (idx == 0) {
    float loss = ws[OFF_LOSS];
    out[(size_t)N * D_ + N] = 0.25f * loss / ((float)N * (float)D_);
  }
}

extern "C" void kernel_launch(void* const* d_in, const int* in_sizes, int n_in,
                              void* d_out, int out_size, void* d_ws, size_t ws_size,
                              hipStream_t stream) {
  // Identify inputs by size (robust to input-order changes).
  const float* h = nullptr; const int* ei = nullptr;
  const float* cb = nullptr; const float* ecnt = nullptr; const float* esum = nullptr;
  long hsz = -1; int hidx = -1;
  for (int i = 0; i < n_in; ++i)
    if ((long)in_sizes[i] > hsz) { hsz = in_sizes[i]; hidx = i; }
  h = (const float*)d_in[hidx];
  const int N = (int)(hsz / D_);
  for (int i = 0; i < n_in; ++i) {
    if (i == hidx) continue;
    const int s = in_sizes[i];
    if (s == N) ei = (const int*)d_in[i];
    else if (s == C_) ecnt = (const float*)d_in[i];
    else if (s == C_ * D_) { if (!cb) cb = (const float*)d_in[i]; else esum = (const float*)d_in[i]; }
  }

  float* out = (float*)d_out;
  float* hq  = out;
  float* at  = out + (size_t)N * D_;

  float* ws = (float*)d_ws;
  float* sums    = ws;
  float* countsF = ws + OFF_COUNTS;
  float* lossp   = ws + OFF_LOSS;
  int*   psumI   = (int*)(ws + OFF_PSUM);
  int*   pcntI   = (int*)(ws + OFF_PCNT);

  const int dopart = (ws_size >= WS_NEED_PART) ? 1 : 0;

  // zero sums/countsF/loss; psum partials fully overwritten
  hipMemsetAsync(d_ws, 0, (size_t)(OFF_LOSS + 1) * 4, stream);

  k_assign_lds<<<256, 1024, 0, stream>>>(h, ei, cb, hq, at, lossp, N);
  k_sums3<<<NCHUNK * 2, 1024, 0, stream>>>(h, at, psumI, pcntI,
                                           sums, countsF, dopart, N);
  if (dopart)
    k_reduce<<<(C_ * D_ + 255) / 256, 256, 0, stream>>>(psumI, pcntI, sums, countsF);
  k_final<<<(C_ * D_ + 255) / 256, 256, 0, stream>>>(cb, ecnt, esum, ws, out, N);
}